// Round 7
// baseline (135.840 us; speedup 1.0000x reference)
//
#include <hip/hip_runtime.h>

#define OUT_DIM 300
#define SLICES  5            // ceil(OUT_DIM/64)
#define SLICE_B 128          // 64 f16 cols per slice row = one full cache line

typedef _Float16 half8_t __attribute__((ext_vector_type(8)));
typedef unsigned int uint32x4_t __attribute__((ext_vector_type(4)));

// ---------------------------------------------------------------------------
// Fused setup — EXACT R1/R2 16B-chunk version (proven).
// Blocks [0, scat_blocks): row_ptr boundary scatter (rows sorted).
// Remainder: repack fp32 weights -> f16, 5 slices of 64 cols (row padded to
// 320), slice-major: wf[(s*in_dim + r)*128 + kc*16]. One thread per 16B chunk.
__global__ __launch_bounds__(256) void setup5_kernel(
    const int* __restrict__ rows, int* __restrict__ row_ptr,
    const float* __restrict__ w, unsigned char* __restrict__ wf,
    int nnz, int batch, int in_dim, int scat_blocks)
{
    if ((int)blockIdx.x < scat_blocks) {
        int i = blockIdx.x * 256 + threadIdx.x;
        if (i >= nnz) return;
        int r = rows[i];
        int prev = (i == 0) ? -1 : rows[i - 1];
        for (int q = prev + 1; q <= r; ++q) row_ptr[q] = i;
        if (i == nnz - 1)
            for (int q = r + 1; q <= batch; ++q) row_ptr[q] = nnz;
        return;
    }
    int j = ((int)blockIdx.x - scat_blocks) * 256 + threadIdx.x;
    if (j >= in_dim * (SLICES * 8)) return;      // 40 chunks of 16B per row
    int r   = j / 40;
    int c16 = j - r * 40;                        // 16B chunk index, 0..39
    int s   = c16 >> 3;                          // slice 0..4
    int kc  = c16 & 7;                           // chunk within slice
    int c0  = c16 * 8;                           // first source col (0..312)
    const float* wr = w + (size_t)r * OUT_DIM + c0;
    float4 f0 = make_float4(0.f, 0.f, 0.f, 0.f);
    float4 f1 = make_float4(0.f, 0.f, 0.f, 0.f);
    if (c0 + 4 <= OUT_DIM) f0 = *(const float4*)wr;        // rows 16B-aligned
    if (c0 + 8 <= OUT_DIM) f1 = *(const float4*)(wr + 4);
    half8_t h;
    h[0] = (_Float16)f0.x; h[1] = (_Float16)f0.y;
    h[2] = (_Float16)f0.z; h[3] = (_Float16)f0.w;
    h[4] = (_Float16)f1.x; h[5] = (_Float16)f1.y;
    h[6] = (_Float16)f1.z; h[7] = (_Float16)f1.w;
    *(half8_t*)(wf + ((size_t)s * in_dim + r) * SLICE_B + kc * 16) = h;
}

// ---------------------------------------------------------------------------
// Persistent-wave pipelined SpMM — R2/R6 structure. ONE change vs R6: exact
// quantum-8 rounds. Base GATHER2 (rounds 0,1: keeps 2 loads in flight), then
// single-instruction GATHER1 appends at 16/24/32/40/48/56 — the twice-proven
// wave-uniform conditional-append shape (loads unconditional inside blocks).
// E[rounds/item]: 4.94 -> 4.47 (-9.5% issued gather-lane slots).
// Confirmed model: time tracks issued gather lanes @ ~1 slot/cyc/CU.
// R3/R4 lessons stand: no branches between load issue and use; no multi-body
// switches over alternative gather bodies.
__global__ __launch_bounds__(256, 8) void spmm5p(
    const int* __restrict__ row_ptr,
    const int* __restrict__ cols,
    const float* __restrict__ vals,
    const unsigned char* __restrict__ wf,
    const float* __restrict__ bias,
    float* __restrict__ out,
    int batch, int in_dim, int rowgroups)
{
    __shared__ uint2 sh[4][64];

    const int items = SLICES * rowgroups;
    const int q8  = items >> 3, rm = items & 7;
    const int xcd = (int)blockIdx.x & 7;
    const int bi  = (int)blockIdx.x >> 3;
    const int bpx = (int)gridDim.x >> 3;         // blocks per XCD (256)
    const int it_lo = (xcd < rm) ? xcd * (q8 + 1)
                                 : rm * (q8 + 1) + (xcd - rm) * q8;
    const int it_hi = it_lo + ((xcd < rm) ? (q8 + 1) : q8);

    const int wave  = threadIdx.x >> 6;
    const int lane  = threadIdx.x & 63;
    const int grp   = lane >> 3;            // which nnz of the round
    const int choff = (lane & 7) * 16;      // byte chunk within the 128B line
    uint2* shw = sh[wave];                  // wave-private: no __syncthreads

    int it = it_lo + bi;
    if (it >= it_hi) return;

    // prologue: first item's extent + chunk0 cols/vals
    int slice = it / rowgroups;
    int row   = (it - slice * rowgroups) * 4 + wave;
    int lo = 0, hi = 0;
    if (row < batch) { lo = row_ptr[row]; hi = row_ptr[row + 1]; }
    uint2 ov;
    {
        int cnt = hi - lo; if (cnt > 64) cnt = 64;
        if (lane < cnt) {
            ov.x = (unsigned)cols[lo + lane] * SLICE_B;
            ov.y = __float_as_uint(vals[lo + lane]);
        } else { ov.x = 0x40000000u; ov.y = 0u; }  // OOB: load 0, no traffic
    }

#define FMA8(M, VB)                                            \
    do {                                                       \
        float v_ = __uint_as_float(VB);                        \
        half8_t wv_ = __builtin_bit_cast(half8_t, (M));        \
        a0 += v_ * (float)wv_[0]; a1 += v_ * (float)wv_[1];    \
        a2 += v_ * (float)wv_[2]; a3 += v_ * (float)wv_[3];    \
        a4 += v_ * (float)wv_[4]; a5 += v_ * (float)wv_[5];    \
        a6 += v_ * (float)wv_[6]; a7 += v_ * (float)wv_[7];    \
    } while (0)

// straight-line: 2 loads issued back-to-back (grouped vmcnt), then 2 FMA8s
#define GATHER2(R0)                                                           \
    do {                                                                      \
        uint2 qa = shw[8 * (R0) + grp], qb = shw[8 * ((R0) + 1) + grp];       \
        uint32x4_t ma = __builtin_amdgcn_raw_buffer_load_b128(                \
            rsrc, (int)(qa.x + choff), 0, 1);                                 \
        uint32x4_t mb = __builtin_amdgcn_raw_buffer_load_b128(                \
            rsrc, (int)(qb.x + choff), 0, 1);                                 \
        FMA8(ma, qa.y); FMA8(mb, qb.y);                                       \
    } while (0)

// single-round append: 1 load + 1 FMA8
#define GATHER1(R0)                                                           \
    do {                                                                      \
        uint2 qa = shw[8 * (R0) + grp];                                       \
        uint32x4_t ma = __builtin_amdgcn_raw_buffer_load_b128(                \
            rsrc, (int)(qa.x + choff), 0, 1);                                 \
        FMA8(ma, qa.y);                                                       \
    } while (0)

#define PROCESS(CNT)                                                          \
    do {                                                                      \
        GATHER2(0);                                                           \
        if ((CNT) > 16) GATHER1(2);                                           \
        if ((CNT) > 24) GATHER1(3);                                           \
        if ((CNT) > 32) GATHER1(4);                                           \
        if ((CNT) > 40) GATHER1(5);                                           \
        if ((CNT) > 48) GATHER1(6);                                           \
        if ((CNT) > 56) GATHER1(7);                                           \
    } while (0)

    while (true) {
        const int  it_next   = it + bpx;
        const bool have_next = it_next < it_hi;   // block-uniform

        __amdgpu_buffer_rsrc_t rsrc = __builtin_amdgcn_make_buffer_rsrc(
            (void*)(wf + (size_t)slice * in_dim * SLICE_B), (short)0,
            in_dim * SLICE_B, 0x00020000);

        // next item's row_ptr loads (latency hides under gather+FMA phase)
        int nslice = 0, nrow = 0, nlo = 0, nhi = 0;
        if (have_next) {
            nslice = it_next / rowgroups;
            nrow   = (it_next - nslice * rowgroups) * 4 + wave;
            if (nrow < batch) { nlo = row_ptr[nrow]; nhi = row_ptr[nrow + 1]; }
        }

        float a0 = 0.f, a1 = 0.f, a2 = 0.f, a3 = 0.f;
        float a4 = 0.f, a5 = 0.f, a6 = 0.f, a7 = 0.f;

        // chunk 0: cols/vals already in registers
        int cnt0 = hi - lo; if (cnt0 > 64) cnt0 = 64;
        shw[lane] = ov;
        PROCESS(cnt0);

        // rare extra chunks (rows with >64 nnz)
        for (int base = lo + 64; base < hi; base += 64) {
            int c2 = hi - base; if (c2 > 64) c2 = 64;
            uint2 o2;
            if (lane < c2) {
                o2.x = (unsigned)cols[base + lane] * SLICE_B;
                o2.y = __float_as_uint(vals[base + lane]);
            } else { o2.x = 0x40000000u; o2.y = 0u; }
            shw[lane] = o2;
            PROCESS(c2);
        }

        // next item's cols/vals (latency hides under fold+store)
        uint2 nov; nov.x = 0x40000000u; nov.y = 0u;
        if (have_next) {
            int ncnt = nhi - nlo; if (ncnt > 64) ncnt = 64;
            if (lane < ncnt) {
                nov.x = (unsigned)cols[nlo + lane] * SLICE_B;
                nov.y = __float_as_uint(vals[nlo + lane]);
            }
        }

        // epilogue: fold 8 groups; lanes 0..7 hold full 8-col sums
        a0 += __shfl_down(a0, 32); a1 += __shfl_down(a1, 32);
        a2 += __shfl_down(a2, 32); a3 += __shfl_down(a3, 32);
        a4 += __shfl_down(a4, 32); a5 += __shfl_down(a5, 32);
        a6 += __shfl_down(a6, 32); a7 += __shfl_down(a7, 32);
        a0 += __shfl_down(a0, 16); a1 += __shfl_down(a1, 16);
        a2 += __shfl_down(a2, 16); a3 += __shfl_down(a3, 16);
        a4 += __shfl_down(a4, 16); a5 += __shfl_down(a5, 16);
        a6 += __shfl_down(a6, 16); a7 += __shfl_down(a7, 16);
        a0 += __shfl_down(a0, 8);  a1 += __shfl_down(a1, 8);
        a2 += __shfl_down(a2, 8);  a3 += __shfl_down(a3, 8);
        a4 += __shfl_down(a4, 8);  a5 += __shfl_down(a5, 8);
        a6 += __shfl_down(a6, 8);  a7 += __shfl_down(a7, 8);

        if (lane < 8 && row < batch) {
            const int col = slice * 64 + lane * 8;
            if (col + 4 <= OUT_DIM) {               // slice 4 tail: lanes 6,7 idle
                float* orow = out + (size_t)row * OUT_DIM + col;
                const float4 b0 = *(const float4*)(bias + col);
                float4 s0;
                s0.x = fmaxf(a0 + b0.x, 0.f);
                s0.y = fmaxf(a1 + b0.y, 0.f);
                s0.z = fmaxf(a2 + b0.z, 0.f);
                s0.w = fmaxf(a3 + b0.w, 0.f);
                *(float4*)orow = s0;
                if (col + 8 <= OUT_DIM) {           // lane5@slice4: cols 296..299
                    const float4 b1 = *(const float4*)(bias + col + 4);
                    float4 s1;
                    s1.x = fmaxf(a4 + b1.x, 0.f);
                    s1.y = fmaxf(a5 + b1.y, 0.f);
                    s1.z = fmaxf(a6 + b1.z, 0.f);
                    s1.w = fmaxf(a7 + b1.w, 0.f);
                    *(float4*)(orow + 4) = s1;
                }
            }
        }

        if (!have_next) break;
        it = it_next; slice = nslice; row = nrow;
        lo = nlo; hi = nhi; ov = nov;
    }
#undef PROCESS
#undef GATHER1
#undef GATHER2
#undef FMA8
}

// ---------------------------------------------------------------------------
// Last-resort fp32 path (tiny ws).
__global__ __launch_bounds__(256) void row_ptr_scatter(
    const int* __restrict__ rows, int* __restrict__ row_ptr, int nnz, int batch)
{
    int i = blockIdx.x * 256 + threadIdx.x;
    if (i >= nnz) return;
    int r = rows[i];
    int prev = (i == 0) ? -1 : rows[i - 1];
    for (int q = prev + 1; q <= r; ++q) row_ptr[q] = i;
    if (i == nnz - 1)
        for (int q = r + 1; q <= batch; ++q) row_ptr[q] = nnz;
}

__global__ __launch_bounds__(256) void spmm_wave_f32_kernel(
    const int* __restrict__ row_ptr,
    const int* __restrict__ cols,
    const float* __restrict__ vals,
    const float* __restrict__ weights,
    const float* __restrict__ bias,
    float* __restrict__ out,
    int batch)
{
    const int wave = threadIdx.x >> 6;
    const int lane = threadIdx.x & 63;
    const int row  = blockIdx.x * 4 + wave;
    if (row >= batch) return;

    const int lo = row_ptr[row];
    const int hi = row_ptr[row + 1];
    float4 acc0 = make_float4(0.f, 0.f, 0.f, 0.f);
    float4 acc1 = make_float4(0.f, 0.f, 0.f, 0.f);
    const bool tail = (lane < 75 - 64);

    for (int base = lo; base < hi; base += 64) {
        const int rem = hi - base;
        const int cnt = rem < 64 ? rem : 64;
        int   c = 0;
        float v = 0.0f;
        if (lane < cnt) { c = cols[base + lane]; v = vals[base + lane]; }
        const int rounds = (cnt + 7) & ~7;
        for (int k = 0; k < rounds; k += 8) {
#pragma unroll
            for (int u = 0; u < 8; ++u) {
                const int   cc = __shfl(c, k + u);
                const float vv = __shfl(v, k + u);
                const float4* wrow = (const float4*)(weights + (size_t)cc * OUT_DIM);
                float4 w0 = wrow[lane];
                acc0.x += vv * w0.x; acc0.y += vv * w0.y;
                acc0.z += vv * w0.z; acc0.w += vv * w0.w;
                if (tail) {
                    float4 w1 = wrow[64 + lane];
                    acc1.x += vv * w1.x; acc1.y += vv * w1.y;
                    acc1.z += vv * w1.z; acc1.w += vv * w1.w;
                }
            }
        }
    }

    const float4* b4 = (const float4*)bias;
    float4* orow = (float4*)(out + (size_t)row * OUT_DIM);
    float4 b0 = b4[lane];
    float4 r0;
    r0.x = fmaxf(acc0.x + b0.x, 0.f);
    r0.y = fmaxf(acc0.y + b0.y, 0.f);
    r0.z = fmaxf(acc0.z + b0.z, 0.f);
    r0.w = fmaxf(acc0.w + b0.w, 0.f);
    orow[lane] = r0;
    if (tail) {
        float4 b1 = b4[64 + lane];
        float4 r1;
        r1.x = fmaxf(acc1.x + b1.x, 0.f);
        r1.y = fmaxf(acc1.y + b1.y, 0.f);
        r1.z = fmaxf(acc1.z + b1.z, 0.f);
        r1.w = fmaxf(acc1.w + b1.w, 0.f);
        orow[64 + lane] = r1;
    }
}

// ---------------------------------------------------------------------------
extern "C" void kernel_launch(void* const* d_in, const int* in_sizes, int n_in,
                              void* d_out, int out_size, void* d_ws, size_t ws_size,
                              hipStream_t stream) {
    const int*   sp_rows = (const int*)d_in[0];
    const int*   sp_cols = (const int*)d_in[1];
    const float* sp_vals = (const float*)d_in[2];
    const float* weights = (const float*)d_in[3];
    const float* bias    = (const float*)d_in[4];
    float* out = (float*)d_out;

    const int nnz    = in_sizes[0];
    const int w_elts = in_sizes[3];
    const int in_dim = w_elts / OUT_DIM;           // 30000
    const int batch  = out_size / OUT_DIM;         // 16384

    size_t rp_bytes = (size_t)(batch + 1) * sizeof(int);
    size_t wf_off   = (rp_bytes + 255) & ~(size_t)255;
    size_t need5    = wf_off + (size_t)in_dim * SLICES * SLICE_B + 256;  // 19.2 MB

    int* row_ptr = (int*)d_ws;
    const int rowgroups = (batch + 3) / 4;

    if (ws_size >= need5) {
        unsigned char* wf = (unsigned char*)d_ws + wf_off;
        const int scat_blocks = (nnz + 255) / 256;
        const int rep_blocks  = (in_dim * (SLICES * 8) + 255) / 256;
        setup5_kernel<<<scat_blocks + rep_blocks, 256, 0, stream>>>(
            sp_rows, row_ptr, weights, wf, nnz, batch, in_dim, scat_blocks);
        // 2048 blocks = 8/CU on 256 CUs, fully co-resident persistent (R2-proven)
        spmm5p<<<2048, 256, 0, stream>>>(
            row_ptr, sp_cols, sp_vals, wf, bias, out, batch, in_dim, rowgroups);
    } else {
        row_ptr_scatter<<<(nnz + 255) / 256, 256, 0, stream>>>(
            sp_rows, row_ptr, nnz, batch);
        spmm_wave_f32_kernel<<<(batch + 3) / 4, 256, 0, stream>>>(
            row_ptr, sp_cols, sp_vals, weights, bias, out, batch);
    }
}

// Round 8
// 131.501 us; speedup vs baseline: 1.0330x; 1.0330x over previous
//
#include <hip/hip_runtime.h>

#define OUT_DIM 300
#define SLICES  5            // ceil(OUT_DIM/64)
#define SLICE_B 128          // 64 f16 cols per slice row = one full cache line

typedef _Float16 half8_t __attribute__((ext_vector_type(8)));
typedef unsigned int uint32x4_t __attribute__((ext_vector_type(4)));

// ---------------------------------------------------------------------------
// Fused setup — EXACT R1/R2 16B-chunk version (proven).
// Blocks [0, scat_blocks): row_ptr boundary scatter (rows sorted).
// Remainder: repack fp32 weights -> f16, 5 slices of 64 cols (row padded to
// 320), slice-major: wf[(s*in_dim + r)*128 + kc*16]. One thread per 16B chunk.
__global__ __launch_bounds__(256) void setup5_kernel(
    const int* __restrict__ rows, int* __restrict__ row_ptr,
    const float* __restrict__ w, unsigned char* __restrict__ wf,
    int nnz, int batch, int in_dim, int scat_blocks)
{
    if ((int)blockIdx.x < scat_blocks) {
        int i = blockIdx.x * 256 + threadIdx.x;
        if (i >= nnz) return;
        int r = rows[i];
        int prev = (i == 0) ? -1 : rows[i - 1];
        for (int q = prev + 1; q <= r; ++q) row_ptr[q] = i;
        if (i == nnz - 1)
            for (int q = r + 1; q <= batch; ++q) row_ptr[q] = nnz;
        return;
    }
    int j = ((int)blockIdx.x - scat_blocks) * 256 + threadIdx.x;
    if (j >= in_dim * (SLICES * 8)) return;      // 40 chunks of 16B per row
    int r   = j / 40;
    int c16 = j - r * 40;                        // 16B chunk index, 0..39
    int s   = c16 >> 3;                          // slice 0..4
    int kc  = c16 & 7;                           // chunk within slice
    int c0  = c16 * 8;                           // first source col (0..312)
    const float* wr = w + (size_t)r * OUT_DIM + c0;
    float4 f0 = make_float4(0.f, 0.f, 0.f, 0.f);
    float4 f1 = make_float4(0.f, 0.f, 0.f, 0.f);
    if (c0 + 4 <= OUT_DIM) f0 = *(const float4*)wr;        // rows 16B-aligned
    if (c0 + 8 <= OUT_DIM) f1 = *(const float4*)(wr + 4);
    half8_t h;
    h[0] = (_Float16)f0.x; h[1] = (_Float16)f0.y;
    h[2] = (_Float16)f0.z; h[3] = (_Float16)f0.w;
    h[4] = (_Float16)f1.x; h[5] = (_Float16)f1.y;
    h[6] = (_Float16)f1.z; h[7] = (_Float16)f1.w;
    *(half8_t*)(wf + ((size_t)s * in_dim + r) * SLICE_B + kc * 16) = h;
}

// ---------------------------------------------------------------------------
// Persistent-wave pipelined SpMM. R8: same issued-lane count as R6
// (E[rounds]≈5.0) but deeper MLP on the common path: base GATHER4 (4 loads
// back-to-back — R2's proven block), then conditional GATHER2 appends at
// 32/48. R7 lesson: GATHER1 appends serialize (1 load in flight) and lose
// more to latency than their lane saving. R3/R4 lessons: no branches between
// load issue and use; no multi-body switches.
__global__ __launch_bounds__(256, 8) void spmm5p(
    const int* __restrict__ row_ptr,
    const int* __restrict__ cols,
    const float* __restrict__ vals,
    const unsigned char* __restrict__ wf,
    const float* __restrict__ bias,
    float* __restrict__ out,
    int batch, int in_dim, int rowgroups)
{
    __shared__ uint2 sh[4][64];

    const int items = SLICES * rowgroups;
    const int q8  = items >> 3, rm = items & 7;
    const int xcd = (int)blockIdx.x & 7;
    const int bi  = (int)blockIdx.x >> 3;
    const int bpx = (int)gridDim.x >> 3;         // blocks per XCD (256)
    const int it_lo = (xcd < rm) ? xcd * (q8 + 1)
                                 : rm * (q8 + 1) + (xcd - rm) * q8;
    const int it_hi = it_lo + ((xcd < rm) ? (q8 + 1) : q8);

    const int wave  = threadIdx.x >> 6;
    const int lane  = threadIdx.x & 63;
    const int grp   = lane >> 3;            // which nnz of the round
    const int choff = (lane & 7) * 16;      // byte chunk within the 128B line
    uint2* shw = sh[wave];                  // wave-private: no __syncthreads

    int it = it_lo + bi;
    if (it >= it_hi) return;

    // prologue: first item's extent + chunk0 cols/vals
    int slice = it / rowgroups;
    int row   = (it - slice * rowgroups) * 4 + wave;
    int lo = 0, hi = 0;
    if (row < batch) { lo = row_ptr[row]; hi = row_ptr[row + 1]; }
    uint2 ov;
    {
        int cnt = hi - lo; if (cnt > 64) cnt = 64;
        if (lane < cnt) {
            ov.x = (unsigned)cols[lo + lane] * SLICE_B;
            ov.y = __float_as_uint(vals[lo + lane]);
        } else { ov.x = 0x40000000u; ov.y = 0u; }  // OOB: load 0, no traffic
    }

#define FMA8(M, VB)                                            \
    do {                                                       \
        float v_ = __uint_as_float(VB);                        \
        half8_t wv_ = __builtin_bit_cast(half8_t, (M));        \
        a0 += v_ * (float)wv_[0]; a1 += v_ * (float)wv_[1];    \
        a2 += v_ * (float)wv_[2]; a3 += v_ * (float)wv_[3];    \
        a4 += v_ * (float)wv_[4]; a5 += v_ * (float)wv_[5];    \
        a6 += v_ * (float)wv_[6]; a7 += v_ * (float)wv_[7];    \
    } while (0)

// straight-line: 4 loads issued back-to-back (grouped vmcnt), then 4 FMA8s
#define GATHER4(R0)                                                           \
    do {                                                                      \
        uint2 qa = shw[8 * (R0) + grp], qb = shw[8 * ((R0) + 1) + grp];       \
        uint2 qc = shw[8 * ((R0) + 2) + grp], qd = shw[8 * ((R0) + 3) + grp]; \
        uint32x4_t ma = __builtin_amdgcn_raw_buffer_load_b128(                \
            rsrc, (int)(qa.x + choff), 0, 1);                                 \
        uint32x4_t mb = __builtin_amdgcn_raw_buffer_load_b128(                \
            rsrc, (int)(qb.x + choff), 0, 1);                                 \
        uint32x4_t mc = __builtin_amdgcn_raw_buffer_load_b128(                \
            rsrc, (int)(qc.x + choff), 0, 1);                                 \
        uint32x4_t md = __builtin_amdgcn_raw_buffer_load_b128(                \
            rsrc, (int)(qd.x + choff), 0, 1);                                 \
        FMA8(ma, qa.y); FMA8(mb, qb.y); FMA8(mc, qc.y); FMA8(md, qd.y);       \
    } while (0)

// straight-line: 2 loads issued back-to-back, then 2 FMA8s
#define GATHER2(R0)                                                           \
    do {                                                                      \
        uint2 qa = shw[8 * (R0) + grp], qb = shw[8 * ((R0) + 1) + grp];       \
        uint32x4_t ma = __builtin_amdgcn_raw_buffer_load_b128(                \
            rsrc, (int)(qa.x + choff), 0, 1);                                 \
        uint32x4_t mb = __builtin_amdgcn_raw_buffer_load_b128(                \
            rsrc, (int)(qb.x + choff), 0, 1);                                 \
        FMA8(ma, qa.y); FMA8(mb, qb.y);                                       \
    } while (0)

#define PROCESS(CNT)                                                          \
    do {                                                                      \
        GATHER4(0);                                                           \
        if ((CNT) > 32) GATHER2(4);                                           \
        if ((CNT) > 48) GATHER2(6);                                           \
    } while (0)

    while (true) {
        const int  it_next   = it + bpx;
        const bool have_next = it_next < it_hi;   // block-uniform

        __amdgpu_buffer_rsrc_t rsrc = __builtin_amdgcn_make_buffer_rsrc(
            (void*)(wf + (size_t)slice * in_dim * SLICE_B), (short)0,
            in_dim * SLICE_B, 0x00020000);

        // next item's row_ptr loads (latency hides under gather+FMA phase)
        int nslice = 0, nrow = 0, nlo = 0, nhi = 0;
        if (have_next) {
            nslice = it_next / rowgroups;
            nrow   = (it_next - nslice * rowgroups) * 4 + wave;
            if (nrow < batch) { nlo = row_ptr[nrow]; nhi = row_ptr[nrow + 1]; }
        }

        float a0 = 0.f, a1 = 0.f, a2 = 0.f, a3 = 0.f;
        float a4 = 0.f, a5 = 0.f, a6 = 0.f, a7 = 0.f;

        // chunk 0: cols/vals already in registers
        int cnt0 = hi - lo; if (cnt0 > 64) cnt0 = 64;
        shw[lane] = ov;
        PROCESS(cnt0);

        // rare extra chunks (rows with >64 nnz)
        for (int base = lo + 64; base < hi; base += 64) {
            int c2 = hi - base; if (c2 > 64) c2 = 64;
            uint2 o2;
            if (lane < c2) {
                o2.x = (unsigned)cols[base + lane] * SLICE_B;
                o2.y = __float_as_uint(vals[base + lane]);
            } else { o2.x = 0x40000000u; o2.y = 0u; }
            shw[lane] = o2;
            PROCESS(c2);
        }

        // next item's cols/vals (latency hides under fold+store)
        uint2 nov; nov.x = 0x40000000u; nov.y = 0u;
        if (have_next) {
            int ncnt = nhi - nlo; if (ncnt > 64) ncnt = 64;
            if (lane < ncnt) {
                nov.x = (unsigned)cols[nlo + lane] * SLICE_B;
                nov.y = __float_as_uint(vals[nlo + lane]);
            }
        }

        // epilogue: fold 8 groups; lanes 0..7 hold full 8-col sums
        a0 += __shfl_down(a0, 32); a1 += __shfl_down(a1, 32);
        a2 += __shfl_down(a2, 32); a3 += __shfl_down(a3, 32);
        a4 += __shfl_down(a4, 32); a5 += __shfl_down(a5, 32);
        a6 += __shfl_down(a6, 32); a7 += __shfl_down(a7, 32);
        a0 += __shfl_down(a0, 16); a1 += __shfl_down(a1, 16);
        a2 += __shfl_down(a2, 16); a3 += __shfl_down(a3, 16);
        a4 += __shfl_down(a4, 16); a5 += __shfl_down(a5, 16);
        a6 += __shfl_down(a6, 16); a7 += __shfl_down(a7, 16);
        a0 += __shfl_down(a0, 8);  a1 += __shfl_down(a1, 8);
        a2 += __shfl_down(a2, 8);  a3 += __shfl_down(a3, 8);
        a4 += __shfl_down(a4, 8);  a5 += __shfl_down(a5, 8);
        a6 += __shfl_down(a6, 8);  a7 += __shfl_down(a7, 8);

        if (lane < 8 && row < batch) {
            const int col = slice * 64 + lane * 8;
            if (col + 4 <= OUT_DIM) {               // slice 4 tail: lanes 6,7 idle
                float* orow = out + (size_t)row * OUT_DIM + col;
                const float4 b0 = *(const float4*)(bias + col);
                float4 s0;
                s0.x = fmaxf(a0 + b0.x, 0.f);
                s0.y = fmaxf(a1 + b0.y, 0.f);
                s0.z = fmaxf(a2 + b0.z, 0.f);
                s0.w = fmaxf(a3 + b0.w, 0.f);
                *(float4*)orow = s0;
                if (col + 8 <= OUT_DIM) {           // lane5@slice4: cols 296..299
                    const float4 b1 = *(const float4*)(bias + col + 4);
                    float4 s1;
                    s1.x = fmaxf(a4 + b1.x, 0.f);
                    s1.y = fmaxf(a5 + b1.y, 0.f);
                    s1.z = fmaxf(a6 + b1.z, 0.f);
                    s1.w = fmaxf(a7 + b1.w, 0.f);
                    *(float4*)(orow + 4) = s1;
                }
            }
        }

        if (!have_next) break;
        it = it_next; slice = nslice; row = nrow;
        lo = nlo; hi = nhi; ov = nov;
    }
#undef PROCESS
#undef GATHER2
#undef GATHER4
#undef FMA8
}

// ---------------------------------------------------------------------------
// Last-resort fp32 path (tiny ws).
__global__ __launch_bounds__(256) void row_ptr_scatter(
    const int* __restrict__ rows, int* __restrict__ row_ptr, int nnz, int batch)
{
    int i = blockIdx.x * 256 + threadIdx.x;
    if (i >= nnz) return;
    int r = rows[i];
    int prev = (i == 0) ? -1 : rows[i - 1];
    for (int q = prev + 1; q <= r; ++q) row_ptr[q] = i;
    if (i == nnz - 1)
        for (int q = r + 1; q <= batch; ++q) row_ptr[q] = nnz;
}

__global__ __launch_bounds__(256) void spmm_wave_f32_kernel(
    const int* __restrict__ row_ptr,
    const int* __restrict__ cols,
    const float* __restrict__ vals,
    const float* __restrict__ weights,
    const float* __restrict__ bias,
    float* __restrict__ out,
    int batch)
{
    const int wave = threadIdx.x >> 6;
    const int lane = threadIdx.x & 63;
    const int row  = blockIdx.x * 4 + wave;
    if (row >= batch) return;

    const int lo = row_ptr[row];
    const int hi = row_ptr[row + 1];
    float4 acc0 = make_float4(0.f, 0.f, 0.f, 0.f);
    float4 acc1 = make_float4(0.f, 0.f, 0.f, 0.f);
    const bool tail = (lane < 75 - 64);

    for (int base = lo; base < hi; base += 64) {
        const int rem = hi - base;
        const int cnt = rem < 64 ? rem : 64;
        int   c = 0;
        float v = 0.0f;
        if (lane < cnt) { c = cols[base + lane]; v = vals[base + lane]; }
        const int rounds = (cnt + 7) & ~7;
        for (int k = 0; k < rounds; k += 8) {
#pragma unroll
            for (int u = 0; u < 8; ++u) {
                const int   cc = __shfl(c, k + u);
                const float vv = __shfl(v, k + u);
                const float4* wrow = (const float4*)(weights + (size_t)cc * OUT_DIM);
                float4 w0 = wrow[lane];
                acc0.x += vv * w0.x; acc0.y += vv * w0.y;
                acc0.z += vv * w0.z; acc0.w += vv * w0.w;
                if (tail) {
                    float4 w1 = wrow[64 + lane];
                    acc1.x += vv * w1.x; acc1.y += vv * w1.y;
                    acc1.z += vv * w1.z; acc1.w += vv * w1.w;
                }
            }
        }
    }

    const float4* b4 = (const float4*)bias;
    float4* orow = (float4*)(out + (size_t)row * OUT_DIM);
    float4 b0 = b4[lane];
    float4 r0;
    r0.x = fmaxf(acc0.x + b0.x, 0.f);
    r0.y = fmaxf(acc0.y + b0.y, 0.f);
    r0.z = fmaxf(acc0.z + b0.z, 0.f);
    r0.w = fmaxf(acc0.w + b0.w, 0.f);
    orow[lane] = r0;
    if (tail) {
        float4 b1 = b4[64 + lane];
        float4 r1;
        r1.x = fmaxf(acc1.x + b1.x, 0.f);
        r1.y = fmaxf(acc1.y + b1.y, 0.f);
        r1.z = fmaxf(acc1.z + b1.z, 0.f);
        r1.w = fmaxf(acc1.w + b1.w, 0.f);
        orow[64 + lane] = r1;
    }
}

// ---------------------------------------------------------------------------
extern "C" void kernel_launch(void* const* d_in, const int* in_sizes, int n_in,
                              void* d_out, int out_size, void* d_ws, size_t ws_size,
                              hipStream_t stream) {
    const int*   sp_rows = (const int*)d_in[0];
    const int*   sp_cols = (const int*)d_in[1];
    const float* sp_vals = (const float*)d_in[2];
    const float* weights = (const float*)d_in[3];
    const float* bias    = (const float*)d_in[4];
    float* out = (float*)d_out;

    const int nnz    = in_sizes[0];
    const int w_elts = in_sizes[3];
    const int in_dim = w_elts / OUT_DIM;           // 30000
    const int batch  = out_size / OUT_DIM;         // 16384

    size_t rp_bytes = (size_t)(batch + 1) * sizeof(int);
    size_t wf_off   = (rp_bytes + 255) & ~(size_t)255;
    size_t need5    = wf_off + (size_t)in_dim * SLICES * SLICE_B + 256;  // 19.2 MB

    int* row_ptr = (int*)d_ws;
    const int rowgroups = (batch + 3) / 4;

    if (ws_size >= need5) {
        unsigned char* wf = (unsigned char*)d_ws + wf_off;
        const int scat_blocks = (nnz + 255) / 256;
        const int rep_blocks  = (in_dim * (SLICES * 8) + 255) / 256;
        setup5_kernel<<<scat_blocks + rep_blocks, 256, 0, stream>>>(
            sp_rows, row_ptr, weights, wf, nnz, batch, in_dim, scat_blocks);
        // 2048 blocks = 8/CU on 256 CUs, fully co-resident persistent (R2-proven)
        spmm5p<<<2048, 256, 0, stream>>>(
            row_ptr, sp_cols, sp_vals, wf, bias, out, batch, in_dim, rowgroups);
    } else {
        row_ptr_scatter<<<(nnz + 255) / 256, 256, 0, stream>>>(
            sp_rows, row_ptr, nnz, batch);
        spmm_wave_f32_kernel<<<(batch + 3) / 4, 256, 0, stream>>>(
            row_ptr, sp_cols, sp_vals, weights, bias, out, batch);
    }
}